// Round 1
// baseline (387.505 us; speedup 1.0000x reference)
//
#include <hip/hip_runtime.h>
#include <hip/hip_bf16.h>
#include <stdint.h>

#define T_SEQ   2048
#define NHEAD   16
#define D_QK    192
#define NPAD1   3712   // 3072 (q) + 512 (latent) + 64 (k_pe) + 64 pad -> 29*128

typedef short bf16x8 __attribute__((ext_vector_type(8)));
typedef float f32x4  __attribute__((ext_vector_type(4)));

__device__ __forceinline__ unsigned short f2bf(float f) {
  union { float f; uint32_t u; } v; v.f = f;
  uint32_t u = v.u;
  uint32_t r = u + 0x7FFF + ((u >> 16) & 1);   // RNE
  return (unsigned short)(r >> 16);
}

// ---------------- elementwise convert f32 -> bf16 ----------------
__global__ __launch_bounds__(256) void convert_bf16_kernel(
    const float* __restrict__ in, unsigned short* __restrict__ out, int n) {
  int i = (blockIdx.x * 256 + threadIdx.x) * 4;
  if (i + 3 < n) {
    float4 v = *(const float4*)(in + i);
    ushort4 o;
    o.x = f2bf(v.x); o.y = f2bf(v.y); o.z = f2bf(v.z); o.w = f2bf(v.w);
    *(ushort4*)(out + i) = o;
  }
}

// ------------- tiled transpose f32 (R x C) -> bf16 (C x R) -------------
__global__ __launch_bounds__(256) void transpose_bf16_kernel(
    const float* __restrict__ in, unsigned short* __restrict__ out, int R, int C) {
  __shared__ float tile[32][33];
  int r0 = blockIdx.x * 32, c0 = blockIdx.y * 32;
  int tx = threadIdx.x & 31, ty = threadIdx.x >> 5;  // 32 x 8
  for (int i = 0; i < 4; i++)
    tile[ty + i * 8][tx] = in[(size_t)(r0 + ty + i * 8) * C + c0 + tx];
  __syncthreads();
  for (int i = 0; i < 4; i++) {
    int c = ty + i * 8;
    out[(size_t)(c0 + c) * R + r0 + tx] = f2bf(tile[tx][c]);
  }
}

// ---------------- GEMM: C(MxN) f32 = A(MxK) bf16 @ B^T(NxK) bf16 ----------------
// 128x128 tile, BK=32, 256 threads = 4 waves of 64x64. All dims multiples of tile.
#define LDP 40   // 32 + 8 pad: rows start 2 banks apart pairwise -> 2-way max (free)
__global__ __launch_bounds__(256) void gemm_bt_kernel(
    const unsigned short* __restrict__ A, const unsigned short* __restrict__ B,
    float* __restrict__ C, int M, int N, int K) {
  __shared__ unsigned short Asm[128 * LDP];
  __shared__ unsigned short Bsm[128 * LDP];
  int tid = threadIdx.x, wid = tid >> 6, lane = tid & 63;
  int lrow = lane & 15, lquad = lane >> 4;
  int m0 = blockIdx.x * 128, n0 = blockIdx.y * 128;
  int wm = (wid & 1) * 64, wn = (wid >> 1) * 64;

  f32x4 acc[4][4];
  for (int i = 0; i < 4; i++) for (int j = 0; j < 4; j++) acc[i][j] = (f32x4){0.f,0.f,0.f,0.f};

  // staging: 512 chunks of 8 bf16 per tile; chunk c -> row c>>2, kchunk c&3
  int ca = tid, cb = tid + 256;
  int ra0 = ca >> 2, ka0 = ca & 3, ra1 = cb >> 2, ka1 = cb & 3;

  for (int k0 = 0; k0 < K; k0 += 32) {
    uint4 av0 = *(const uint4*)(A + (size_t)(m0 + ra0) * K + k0 + ka0 * 8);
    uint4 av1 = *(const uint4*)(A + (size_t)(m0 + ra1) * K + k0 + ka1 * 8);
    uint4 bv0 = *(const uint4*)(B + (size_t)(n0 + ra0) * K + k0 + ka0 * 8);
    uint4 bv1 = *(const uint4*)(B + (size_t)(n0 + ra1) * K + k0 + ka1 * 8);
    __syncthreads();   // previous iter's readers done
    *(uint4*)(Asm + ra0 * LDP + ka0 * 8) = av0;
    *(uint4*)(Asm + ra1 * LDP + ka1 * 8) = av1;
    *(uint4*)(Bsm + ra0 * LDP + ka0 * 8) = bv0;
    *(uint4*)(Bsm + ra1 * LDP + ka1 * 8) = bv1;
    __syncthreads();
    bf16x8 af[4], bfr[4];
    for (int mt = 0; mt < 4; mt++)
      af[mt] = *(const bf16x8*)(Asm + (wm + mt * 16 + lrow) * LDP + lquad * 8);
    for (int nt = 0; nt < 4; nt++)
      bfr[nt] = *(const bf16x8*)(Bsm + (wn + nt * 16 + lrow) * LDP + lquad * 8);
    for (int mt = 0; mt < 4; mt++)
      for (int nt = 0; nt < 4; nt++)
        acc[mt][nt] = __builtin_amdgcn_mfma_f32_16x16x32_bf16(af[mt], bfr[nt], acc[mt][nt], 0, 0, 0);
  }
  for (int mt = 0; mt < 4; mt++)
    for (int nt = 0; nt < 4; nt++) {
      int row = m0 + wm + mt * 16 + lquad * 4;
      int col = n0 + wn + nt * 16 + lrow;
      for (int r = 0; r < 4; r++)
        C[(size_t)(row + r) * N + col] = acc[mt][nt][r];
    }
}

// ---------------- postproc1: rmsnorm + rope + pack q_full/k_pe/kv_a ----------------
__global__ __launch_bounds__(256) void postproc1_kernel(
    const float* __restrict__ q_lat,      // T x NPAD1
    const float* __restrict__ ln_w,       // 512
    const int* __restrict__ positions,    // T (int32)
    unsigned short* __restrict__ kv_a,    // T x 512 bf16
    unsigned short* __restrict__ q_full,  // NH x T x 192 bf16 (pre-scaled)
    unsigned short* __restrict__ k_full)  // NH x T x 192 bf16 (rope part only)
{
  int t = blockIdx.x, tid = threadIdx.x;
  const float* row = q_lat + (size_t)t * NPAD1;
  const float scaling = 0.07216878364870323f;  // 192^-0.5

  float v0 = row[3072 + tid], v1 = row[3072 + 256 + tid];
  float ss = v0 * v0 + v1 * v1;
  for (int m = 1; m < 64; m <<= 1) ss += __shfl_xor(ss, m, 64);
  __shared__ float red[4];
  if ((tid & 63) == 0) red[tid >> 6] = ss;
  __shared__ float kro[64];
  float pos = (float)positions[t];
  __syncthreads();
  float rstd = rsqrtf((red[0] + red[1] + red[2] + red[3]) * (1.f / 512.f) + 1e-6f);
  kv_a[(size_t)t * 512 + tid]       = f2bf(v0 * rstd * ln_w[tid]);
  kv_a[(size_t)t * 512 + 256 + tid] = f2bf(v1 * rstd * ln_w[256 + tid]);

  if (tid < 32) {
    float inv_freq = powf(10000.f, -(float)(2 * tid) / 64.f);
    float c, s; sincosf(pos * inv_freq, &s, &c);
    float x1 = row[3584 + 2 * tid], x2 = row[3584 + 2 * tid + 1];
    kro[2 * tid]     = x1 * c - x2 * s;
    kro[2 * tid + 1] = x2 * c + x1 * s;
  }
  __syncthreads();
  for (int i = tid; i < NHEAD * 64; i += 256) {         // k_pe broadcast to heads
    int h = i >> 6, d = i & 63;
    k_full[((size_t)h * T_SEQ + t) * 192 + 128 + d] = f2bf(kro[d]);
  }
  for (int i = tid; i < NHEAD * 128; i += 256) {        // q_nope (scaled)
    int h = i >> 7, d = i & 127;
    q_full[((size_t)h * T_SEQ + t) * 192 + d] = f2bf(row[h * 192 + d] * scaling);
  }
  for (int i = tid; i < NHEAD * 32; i += 256) {         // q_pe rope (scaled)
    int h = i >> 5, p = i & 31;
    float inv_freq = powf(10000.f, -(float)(2 * p) / 64.f);
    float c, s; sincosf(pos * inv_freq, &s, &c);
    float x1 = row[h * 192 + 128 + 2 * p], x2 = row[h * 192 + 128 + 2 * p + 1];
    q_full[((size_t)h * T_SEQ + t) * 192 + 128 + 2 * p]     = f2bf((x1 * c - x2 * s) * scaling);
    q_full[((size_t)h * T_SEQ + t) * 192 + 128 + 2 * p + 1] = f2bf((x2 * c + x1 * s) * scaling);
  }
}

// ---------------- postproc2: split kv -> k_nope (bf16) and v^T (bf16) ----------------
__global__ __launch_bounds__(256) void knope_kernel(
    const float* __restrict__ kv_out, unsigned short* __restrict__ k_full) {
  int i = blockIdx.x * 256 + threadIdx.x;   // over NH*T*128
  int d = i & 127, rest = i >> 7;
  int t = rest & (T_SEQ - 1), h = rest >> 11;
  k_full[((size_t)h * T_SEQ + t) * 192 + d] = f2bf(kv_out[(size_t)t * 4096 + h * 256 + d]);
}

__global__ __launch_bounds__(256) void vtrans_kernel(
    const float* __restrict__ kv_out, unsigned short* __restrict__ v_t) {
  __shared__ float tile[32][33];
  int h = blockIdx.z, t0 = blockIdx.x * 32, d0 = blockIdx.y * 32;
  int tx = threadIdx.x & 31, ty = threadIdx.x >> 5;
  for (int i = 0; i < 4; i++)
    tile[ty + i * 8][tx] = kv_out[(size_t)(t0 + ty + i * 8) * 4096 + h * 256 + 128 + d0 + tx];
  __syncthreads();
  for (int i = 0; i < 4; i++) {
    int d = d0 + ty + i * 8;
    v_t[((size_t)h * 128 + d) * T_SEQ + t0 + tx] = f2bf(tile[tx][ty + i * 8]);
  }
}

// ---------------- flash attention: BM=64, BN=64, 4 waves x 16 rows ----------------
#define KPAD 200   // 192+8
#define VPAD 72    // 64+8
__global__ __launch_bounds__(256) void flash_kernel(
    const unsigned short* __restrict__ q_full,  // NH x T x 192 (pre-scaled by 192^-0.5)
    const unsigned short* __restrict__ k_full,  // NH x T x 192
    const unsigned short* __restrict__ v_t,     // NH x 128 x T
    unsigned short* __restrict__ attn_out)      // T x 2048
{
  __shared__ unsigned short Ksm[64 * KPAD];        // 25600 B
  __shared__ unsigned short Vsm[128 * VPAD];       // 18432 B
  __shared__ unsigned short Psm[4][16 * VPAD];     //  9216 B
  int qb = blockIdx.x, h = blockIdx.y;
  int tid = threadIdx.x, wid = tid >> 6, lane = tid & 63;
  int lrow = lane & 15, lquad = lane >> 4;

  const unsigned short* qh = q_full + (size_t)h * T_SEQ * 192;
  const unsigned short* kh = k_full + (size_t)h * T_SEQ * 192;
  const unsigned short* vh = v_t    + (size_t)h * 128 * T_SEQ;

  bf16x8 qf[6];
  {
    const unsigned short* qrow = qh + (size_t)(qb * 64 + wid * 16 + lrow) * 192 + lquad * 8;
    for (int kc = 0; kc < 6; kc++) qf[kc] = *(const bf16x8*)(qrow + kc * 32);
  }
  f32x4 oacc[8];
  for (int i = 0; i < 8; i++) oacc[i] = (f32x4){0.f,0.f,0.f,0.f};
  float mrow[4], lsum[4];
  for (int r = 0; r < 4; r++) { mrow[r] = -1e30f; lsum[r] = 0.f; }
  int q_row_g = qb * 64 + wid * 16 + lquad * 4;   // + r

  for (int kb = 0; kb <= qb; kb++) {
    __syncthreads();   // previous iter's K/V readers done
    for (int i = 0; i < 6; i++) {                 // K tile: 64 x 192 -> 1536 chunks
      int c = tid + i * 256;
      int kr = c / 24, kc = c % 24;
      uint4 val = *(const uint4*)(kh + (size_t)(kb * 64 + kr) * 192 + kc * 8);
      *(uint4*)(Ksm + kr * KPAD + kc * 8) = val;
    }
    for (int i = 0; i < 4; i++) {                 // V^T tile: 128 x 64 -> 1024 chunks
      int c = tid + i * 256;
      int dr = c >> 3, kc = c & 7;
      uint4 val = *(const uint4*)(vh + (size_t)dr * T_SEQ + kb * 64 + kc * 8);
      *(uint4*)(Vsm + dr * VPAD + kc * 8) = val;
    }
    __syncthreads();

    f32x4 sacc[4];
    for (int nt = 0; nt < 4; nt++) {
      sacc[nt] = (f32x4){0.f,0.f,0.f,0.f};
      for (int kc = 0; kc < 6; kc++) {
        bf16x8 kf = *(const bf16x8*)(Ksm + (nt * 16 + lrow) * KPAD + kc * 32 + lquad * 8);
        sacc[nt] = __builtin_amdgcn_mfma_f32_16x16x32_bf16(qf[kc], kf, sacc[nt], 0, 0, 0);
      }
    }
    int col_base = kb * 64;
    for (int r = 0; r < 4; r++) {
      float mx = -1e30f;
      for (int nt = 0; nt < 4; nt++) {
        int col = col_base + nt * 16 + lrow;
        float s = (col <= q_row_g + r) ? sacc[nt][r] : -1e30f;
        sacc[nt][r] = s;
        mx = fmaxf(mx, s);
      }
      mx = fmaxf(mx, __shfl_xor(mx, 1, 64));
      mx = fmaxf(mx, __shfl_xor(mx, 2, 64));
      mx = fmaxf(mx, __shfl_xor(mx, 4, 64));
      mx = fmaxf(mx, __shfl_xor(mx, 8, 64));
      float mnew = fmaxf(mrow[r], mx);
      float alpha = __expf(mrow[r] - mnew);
      float rs = 0.f;
      for (int nt = 0; nt < 4; nt++) {
        float p = __expf(sacc[nt][r] - mnew);
        sacc[nt][r] = p;
        rs += p;
      }
      rs += __shfl_xor(rs, 1, 64);
      rs += __shfl_xor(rs, 2, 64);
      rs += __shfl_xor(rs, 4, 64);
      rs += __shfl_xor(rs, 8, 64);
      lsum[r] = lsum[r] * alpha + rs;
      mrow[r] = mnew;
      for (int i = 0; i < 8; i++) oacc[i][r] *= alpha;
    }
    // P: C-layout -> LDS -> A-layout (per-wave buffer, no block barrier needed)
    unsigned short* pw = &Psm[wid][0];
    for (int nt = 0; nt < 4; nt++)
      for (int r = 0; r < 4; r++)
        pw[(lquad * 4 + r) * VPAD + nt * 16 + lrow] = f2bf(sacc[nt][r]);
    for (int kc = 0; kc < 2; kc++) {
      bf16x8 pf = *(const bf16x8*)(pw + lrow * VPAD + kc * 32 + lquad * 8);
      for (int ntv = 0; ntv < 8; ntv++) {
        bf16x8 vf = *(const bf16x8*)(Vsm + (ntv * 16 + lrow) * VPAD + kc * 32 + lquad * 8);
        oacc[ntv] = __builtin_amdgcn_mfma_f32_16x16x32_bf16(pf, vf, oacc[ntv], 0, 0, 0);
      }
    }
  }
  for (int r = 0; r < 4; r++) {
    float inv = 1.f / lsum[r];
    int row = qb * 64 + wid * 16 + lquad * 4 + r;
    for (int ntv = 0; ntv < 8; ntv++)
      attn_out[(size_t)row * 2048 + h * 128 + ntv * 16 + lrow] = f2bf(oacc[ntv][r] * inv);
  }
}

// ---------------- launch ----------------
extern "C" void kernel_launch(void* const* d_in, const int* in_sizes, int n_in,
                              void* d_out, int out_size, void* d_ws, size_t ws_size,
                              hipStream_t stream) {
  const int*   positions = (const int*)d_in[0];
  const float* hs     = (const float*)d_in[1];
  const float* w_q    = (const float*)d_in[2];
  const float* w_kv_a = (const float*)d_in[3];
  const float* ln_w   = (const float*)d_in[4];
  const float* w_kv_b = (const float*)d_in[5];
  const float* w_o    = (const float*)d_in[6];
  float* out = (float*)d_out;

  char* ws = (char*)d_ws;
  size_t off = 0;
  auto alloc = [&](size_t bytes) { void* p = ws + off; off += (bytes + 255) & ~(size_t)255; return p; };
  unsigned short* hs_bf   = (unsigned short*)alloc((size_t)2048 * 2048 * 2);
  unsigned short* wcat_t  = (unsigned short*)alloc((size_t)NPAD1 * 2048 * 2);
  float*          q_lat   = (float*)alloc((size_t)2048 * NPAD1 * 4);
  unsigned short* kv_a_bf = (unsigned short*)alloc((size_t)2048 * 512 * 2);
  unsigned short* wkvb_t  = (unsigned short*)alloc((size_t)4096 * 512 * 2);
  float*          kv_out  = (float*)alloc((size_t)2048 * 4096 * 4);
  unsigned short* q_full  = (unsigned short*)alloc((size_t)NHEAD * 2048 * 192 * 2);
  unsigned short* k_full  = (unsigned short*)alloc((size_t)NHEAD * 2048 * 192 * 2);
  unsigned short* v_t     = (unsigned short*)alloc((size_t)NHEAD * 128 * 2048 * 2);
  unsigned short* attn_o  = (unsigned short*)alloc((size_t)2048 * 2048 * 2);
  unsigned short* wo_t    = (unsigned short*)alloc((size_t)2048 * 2048 * 2);

  convert_bf16_kernel<<<4096, 256, 0, stream>>>(hs, hs_bf, 2048 * 2048);
  transpose_bf16_kernel<<<dim3(64, 96),  256, 0, stream>>>(w_q,    wcat_t,                 2048, 3072);
  transpose_bf16_kernel<<<dim3(64, 18),  256, 0, stream>>>(w_kv_a, wcat_t + (size_t)3072 * 2048, 2048, 576);
  transpose_bf16_kernel<<<dim3(16, 128), 256, 0, stream>>>(w_kv_b, wkvb_t,                 512,  4096);
  transpose_bf16_kernel<<<dim3(64, 64),  256, 0, stream>>>(w_o,    wo_t,                   2048, 2048);
  hipMemsetAsync(wcat_t + (size_t)3648 * 2048, 0, (size_t)64 * 2048 * 2, stream);  // pad rows

  gemm_bt_kernel<<<dim3(16, 29), 256, 0, stream>>>(hs_bf, wcat_t, q_lat, 2048, NPAD1, 2048);
  postproc1_kernel<<<2048, 256, 0, stream>>>(q_lat, ln_w, positions, kv_a_bf, q_full, k_full);
  gemm_bt_kernel<<<dim3(16, 32), 256, 0, stream>>>(kv_a_bf, wkvb_t, kv_out, 2048, 4096, 512);
  knope_kernel<<<16384, 256, 0, stream>>>(kv_out, k_full);
  vtrans_kernel<<<dim3(64, 4, 16), 256, 0, stream>>>(kv_out, v_t);
  flash_kernel<<<dim3(32, 16), 256, 0, stream>>>(q_full, k_full, v_t, attn_o);
  gemm_bt_kernel<<<dim3(16, 16), 256, 0, stream>>>(attn_o, wo_t, out, 2048, 2048, 2048);
}